// Round 19
// baseline (142.245 us; speedup 1.0000x reference)
//
#include <hip/hip_runtime.h>
#include <hip/hip_bf16.h>

typedef float f32x4 __attribute__((ext_vector_type(4)));
typedef int   i32x4 __attribute__((ext_vector_type(4)));
typedef int   i32x8 __attribute__((ext_vector_type(8)));

#define NC 4096
#define ND 1024
#define NVP 256     // padded compact-row count (B*A = 256 annotations max)
#define EPSF 1e-10f
#define SCALE1 127  // E8M0 exponent byte for 2^0
#define NBLK 256

// Fragment layout (rounds 8-18 verified): frag = 2048 B;
//   byte = half*1024 + (hi*16+lo)*16 + b, row = R16*16+lo, k = hi*32+half*16+b.
// afrag additionally XOR-swizzles the chunk address with ((half<<2|hi)<<4) on
// BOTH write and read (rule 21) so the per-row ds_write_b16 (64 lanes, one
// row, all (half,hi) combos) spreads across all 32 banks.

// ---------------- K1: 1-block compact + publish + zero (R13-proven scan) ----------------
__global__ __launch_bounds__(256)
void compact_kernel(const int* __restrict__ ann, int n_ann,
                    int* __restrict__ vidx, int* __restrict__ nv,
                    float* __restrict__ accum, int* __restrict__ ticket) {
  __shared__ unsigned char mark[NC];
  __shared__ int wsum[4];
  const int tid = threadIdx.x;
  const int lane = tid & 63, wid = tid >> 6;
  for (int i = tid; i < NC; i += 256) mark[i] = 0;
  __syncthreads();
  for (int t = tid; t < n_ann; t += 256) {
    int idx = ann[t * 5 + 4];
    if (idx >= 0 && idx < NC) mark[idx] = 1;  // benign race: all write 1
  }
  __syncthreads();
  int base = tid * 16, lc = 0;
  #pragma unroll
  for (int k = 0; k < 16; ++k) lc += mark[base + k];
  int inc = lc;
  #pragma unroll
  for (int off = 1; off < 64; off <<= 1) {
    int v = __shfl_up(inc, off);
    if (lane >= off) inc += v;
  }
  if (lane == 63) wsum[wid] = inc;
  __syncthreads();
  int wbase = 0;
  for (int w = 0; w < wid; ++w) wbase += wsum[w];
  int pos = wbase + inc - lc;  // exclusive prefix
  for (int k = 0; k < 16; ++k)
    if (mark[base + k]) vidx[pos++] = base + k;
  const int total = wsum[0] + wsum[1] + wsum[2] + wsum[3];
  if (tid == 0) *nv = total;
  for (int i = total + tid; i < NVP; i += 256) vidx[i] = 0;  // padded -> row 0
  if (tid < 8) accum[tid] = 0.f;   // re-zero every call (graph replay)
  if (tid == 8) *ticket = 0;
}

// ---------------- K2: self-convert (coalesced) + GEMM + loss + ticket finalize ----------------
__global__ __launch_bounds__(512)
void pgemm_kernel(const float* __restrict__ F, const float* __restrict__ P,
                  const int* __restrict__ vidx, const int* __restrict__ nv,
                  float* __restrict__ accum, int* __restrict__ ticket,
                  float* __restrict__ out) {
  __shared__ int vloc[NVP];
  __shared__ float f2loc[NVP];
  __shared__ __attribute__((aligned(16))) unsigned char afrag[16 * 2048];  // F slab/kt
  __shared__ __attribute__((aligned(16))) unsigned char bfrag[8 * 2048];   // P frags
  __shared__ float p2l[16], psl[16], redI[8], redE[8], redN[8];
  const int tid = threadIdx.x;
  const int lane = tid & 63, wid = tid >> 6;
  const int bj = blockIdx.x;  // 16 P rows per block
  const int total = *nv;

  for (int i = tid; i < NVP; i += 512) vloc[i] = vidx[i];

  // ---- P-phase: convert 16 rows -> swizzled bfrag + norms (R17-proven) ----
  {
    const int r = tid >> 5;    // row 0..15
    const int seg = tid & 31;  // float4 lane within row
    const float* src = P + (size_t)(bj * 16 + r) * ND;
    float sq = 0.f, sm = 0.f;
    #pragma unroll
    for (int i = 0; i < 8; ++i) {
      float4 v = *reinterpret_cast<const float4*>(src + (seg + i * 32) * 4);
      int pk = __builtin_amdgcn_cvt_pk_fp8_f32(v.x, v.y, 0, false);
      pk = __builtin_amdgcn_cvt_pk_fp8_f32(v.z, v.w, pk, true);
      int addr = i * 2048 + r * 128 + ((seg * 4) ^ ((r & 7) << 4));
      *reinterpret_cast<int*>(&bfrag[addr]) = pk;
      sq += v.x * v.x + v.y * v.y + v.z * v.z + v.w * v.w;
      sm += v.x + v.y + v.z + v.w;
    }
    #pragma unroll
    for (int off = 16; off; off >>= 1) {
      sq += __shfl_down(sq, off, 32);
      sm += __shfl_down(sm, off, 32);
    }
    if ((tid & 31) == 0) { p2l[r] = sq; psl[r] = sm; }
  }
  __syncthreads();  // bfrag + vloc ready

  // ---- K-loop: coalesced self-convert of F slab (per kt) + MFMA ----
  const int lo = lane & 15, hi = lane >> 4;
  f32x4 acc0 = {0.f, 0.f, 0.f, 0.f}, acc1 = acc0;
  const int fbA = wid * 2;  // wave w owns compact rows [w*32, w*32+32) for MFMA
  const int kl = lane * 2;  // this lane's 2 k-elements within the 128-k window
  const int hi5 = kl >> 5, half = (kl >> 4) & 1, bby = kl & 15;
  const int swz = ((half << 2) | hi5) << 4;
  #pragma unroll 1
  for (int kt = 0; kt < 8; ++kt) {
    __syncthreads();  // previous kt's MFMA reads of afrag complete
    #pragma unroll
    for (int rr = 0; rr < 32; ++rr) {
      const int r = wid + rr * 8;  // wave-interleaved rows: all 64 lanes same row
      const int prow = vloc[r];
      const float* src = F + (size_t)prow * ND + kt * 128 + kl;
      float2 v = *reinterpret_cast<const float2*>(src);  // 8 B/lane, coalesced
      int pk = __builtin_amdgcn_cvt_pk_fp8_f32(v.x, v.y, 0, false);
      int w = half * 1024 + ((((hi5 * 16 + (r & 15)) * 16) ^ swz)) + bby;
      *reinterpret_cast<unsigned short*>(&afrag[(r >> 4) * 2048 + w]) =
          (unsigned short)(pk & 0xffff);
      float sq = v.x * v.x + v.y * v.y;
      #pragma unroll
      for (int off = 32; off; off >>= 1) sq += __shfl_down(sq, off);
      if (lane == 0) f2loc[r] = (kt == 0) ? sq : f2loc[r] + sq;
    }
    __syncthreads();  // afrag + f2loc(kt) ready
    i32x8 a0, a1, b;
    {
      // swizzle-aware A-frag read: half0 at ^((0<<2|hi)<<4), half1 at ^((4|hi)<<4)
      #pragma unroll
      for (int f = 0; f < 2; ++f) {
        const unsigned char* bp = &afrag[(fbA + f) * 2048];
        int c0 = ((hi * 16 + lo) * 16) ^ (hi << 4);
        int c1 = 1024 + (((hi * 16 + lo) * 16) ^ ((4 | hi) << 4));
        i32x4 l0 = *reinterpret_cast<const i32x4*>(bp + c0);
        i32x4 l1 = *reinterpret_cast<const i32x4*>(bp + c1);
        if (f == 0) a0 = __builtin_shufflevector(l0, l1, 0, 1, 2, 3, 4, 5, 6, 7);
        else        a1 = __builtin_shufflevector(l0, l1, 0, 1, 2, 3, 4, 5, 6, 7);
      }
      int x = (lo & 7) << 4;
      const unsigned char* bb = &bfrag[kt * 2048 + lo * 128];
      i32x4 l0 = *reinterpret_cast<const i32x4*>(bb + ((hi * 32) ^ x));
      i32x4 l1 = *reinterpret_cast<const i32x4*>(bb + ((hi * 32 + 16) ^ x));
      b = __builtin_shufflevector(l0, l1, 0, 1, 2, 3, 4, 5, 6, 7);
    }
    acc0 = __builtin_amdgcn_mfma_scale_f32_16x16x128_f8f6f4(
        a0, b, acc0, 0, 0, 0, SCALE1, 0, SCALE1);
    acc1 = __builtin_amdgcn_mfma_scale_f32_16x16x128_f8f6f4(
        a1, b, acc1, 0, 0, 0, SCALE1, 0, SCALE1);
  }

  // ---- Epilogue. C/D: col = lane&15 (P row), row = (lane>>4)*4+reg (F row) ----
  float intra_l = 0.f, inter_l = 0.f;
  {
    const int gj = bj * 16 + lo;
    const float p2j = p2l[lo];
    const bool mj = psl[lo] != 0.f;
    if (mj) {
      #pragma unroll
      for (int f = 0; f < 2; ++f) {
        f32x4 a = f ? acc1 : acc0;
        #pragma unroll
        for (int r = 0; r < 4; ++r) {
          int cc = wid * 32 + f * 16 + hi * 4 + r;
          if (cc < total) {
            float msd = fmaxf(f2loc[cc] + p2j - 2.f * a[r], 0.f) * (1.f / 1024.f);
            int gi = vloc[cc];
            if (gi == gj) {
              intra_l += msd;                 // diagonal: intra
            } else if (msd < 1.0f) {          // inter nonzero only if s<1
              float s = sqrtf(fmaxf(msd, 1e-12f));
              float e = 1.f - s;
              float e2 = e * e;
              inter_l += e2 * e2;             // (e/M)^2 * max(e,0)^2, M=1
            }
          }
        }
      }
    }
  }
  float ndl = 0.f;
  for (int c = tid; c < total; c += 512) {
    int v = vloc[c];
    if ((v >> 4) == bj && psl[v & 15] != 0.f) ndl += 1.f;
  }
  #pragma unroll
  for (int off = 32; off; off >>= 1) {
    intra_l += __shfl_down(intra_l, off);
    inter_l += __shfl_down(inter_l, off);
    ndl     += __shfl_down(ndl, off);
  }
  if (lane == 0) { redI[wid] = intra_l; redE[wid] = inter_l; redN[wid] = ndl; }
  __syncthreads();

  if (tid == 0) {
    float si = 0.f, se = 0.f, nd = 0.f;
    #pragma unroll
    for (int w = 0; w < 8; ++w) { si += redI[w]; se += redE[w]; nd += redN[w]; }
    float nj = 0.f;
    #pragma unroll
    for (int r = 0; r < 16; ++r) nj += (psl[r] != 0.f) ? 1.f : 0.f;
    // Fence-free completion (R17-proven): device-scope atomics hit the global
    // coherence point; wave-local vmcnt(0) orders the ticket after them.
    atomicAdd(&accum[0], si);
    atomicAdd(&accum[1], se);
    atomicAdd(&accum[2], nj);  // exact: integer-valued
    atomicAdd(&accum[3], nd);
    asm volatile("s_waitcnt vmcnt(0)" ::: "memory");
    int tkt = atomicAdd(ticket, 1);
    if (tkt == NBLK - 1) {     // last block: all prior atomics completed
      float a0 = atomicAdd(&accum[0], 0.f);
      float a1 = atomicAdd(&accum[1], 0.f);
      float fnj = atomicAdd(&accum[2], 0.f);
      float fnd = atomicAdd(&accum[3], 0.f);
      float fni = (float)total;
      out[0] = a0 / (fnd + EPSF);
      out[1] = a1 / (fni * fnj - fnd + EPSF);
    }
  }
}

extern "C" void kernel_launch(void* const* d_in, const int* in_sizes, int n_in,
                              void* d_out, int out_size, void* d_ws, size_t ws_size,
                              hipStream_t stream) {
  const float* F = (const float*)d_in[0];
  const float* P = (const float*)d_in[1];
  const int* ann = (const int*)d_in[2];
  int n_ann = in_sizes[2] / 5;

  char* ws = (char*)d_ws;
  float* accum  = (float*)ws;          // 8 f32
  int*   vidx   = (int*)(accum + 8);   // 256 i32
  int*   nv     = vidx + NVP;          // 1 i32
  int*   ticket = nv + 1;              // 1 i32

  float* out = (float*)d_out;

  compact_kernel<<<1, 256, 0, stream>>>(ann, n_ann, vidx, nv, accum, ticket);
  pgemm_kernel<<<NBLK, 512, 0, stream>>>(F, P, vidx, nv, accum, ticket, out);
}